// Round 14
// baseline (102.214 us; speedup 1.0000x reference)
//
#include <hip/hip_runtime.h>
#include <hip/hip_bf16.h>

#define TB 256   // T (sequence length)
#define CC 64    // C (embed)
#define HH 64    // H (head size)

typedef __attribute__((ext_vector_type(8))) short short8;   // 8 bf16 (4 VGPRs)
typedef __attribute__((ext_vector_type(4))) float f32x4;    // MFMA C/D frag

#define MFMA16(a, b, c) __builtin_amdgcn_mfma_f32_16x16x32_bf16((a), (b), (c), 0, 0, 0)

// Packed f32->bf16 pair via HIP intrinsic (lowers to v_cvt_pk_bf16_f32) — proven R12.
__device__ __forceinline__ unsigned cvt2(float lo, float hi) {
    union { __hip_bfloat162 h2; unsigned u; } cv;
    cv.h2 = __float22bfloat162_rn(make_float2(lo, hi));
    return cv.u;
}

union S8U { short8 s8; unsigned u32[4]; unsigned long long u64[2]; };

__device__ __forceinline__ short8 pack8(f32x4 a, f32x4 b) {
    S8U r;
    r.u32[0] = cvt2(a[0], a[1]);
    r.u32[1] = cvt2(a[2], a[3]);
    r.u32[2] = cvt2(b[0], b[1]);
    r.u32[3] = cvt2(b[2], b[3]);
    return r.s8;
}

__device__ __forceinline__ unsigned long long pack4(f32x4 a) {
    S8U r;
    r.u32[0] = cvt2(a[0], a[1]);
    r.u32[1] = cvt2(a[2], a[3]);
    return r.u64[0];
}

// Pre-kernel: W -> MFMA-ready bf16 fragments (proven R4). Layout byte-identical to wb frags.
__global__ __launch_bounds__(512, 1)
void pack_w(const float* __restrict__ Wq, const float* __restrict__ Wk,
            const float* __restrict__ Wv, short8* __restrict__ wf) {
    const int tid  = threadIdx.x;
    const int lane = tid & 63;
    const int lr   = lane & 15;
    const int lg   = lane >> 4;
    const int idx  = tid >> 6;        // 0..7
    const int t    = idx >> 1;
    const int kk   = idx & 1;
    const float* Ws[3] = { Wq, Wk, Wv };
#pragma unroll
    for (int m = 0; m < 3; ++m) {
        const f32x4* p4 = (const f32x4*)(Ws[m] + (16 * t + lr) * CC + kk * 32 + lg * 8);
        wf[((m * 4 + t) * 2 + kk) * 64 + lane] = pack8(p4[0], p4[1]);
    }
}

// R5 structure (16 waves, 1 strip/wave — proven correct) with the register clamp fixed:
// LB(1024,4) gives 64-VGPR budget (R5's LB(1024,8) clamped to 32 -> spills -> regression).
// 64 VGPR x 2048 thr = exact reg budget -> 2 blocks/CU -> 32 waves/CU (vs 16 now).
// + R12's cvt_pk conversions and kexp-folded-into-Q.
template<bool WSF>
__global__ __launch_bounds__(1024, 4)
void attn_fused(const float* __restrict__ x, const float* __restrict__ Wq,
                const float* __restrict__ Wk, const float* __restrict__ Wv,
                const short8* __restrict__ wf, float* __restrict__ out)
{
    // 64 KiB shared, phase-aliased: Phase B/C: kf(32K)+vq(32K); epilogue: fp32 stage[256][64]
    __shared__ __align__(16) char smem[65536];
    short8* kf_lds = (short8*)smem;                                   // [16][2][4][16]
    unsigned long long* vq_lds = (unsigned long long*)(smem + 32768); // [4][64][16]
    float* stage = (float*)smem;

    const int b    = blockIdx.x;
    const int tid  = threadIdx.x;
    const int wave = tid >> 6;        // 0..15 == strip id
    const int lane = tid & 63;
    const int lr   = lane & 15;
    const int lg   = lane >> 4;
    const int xsw  = (lr & 7) << 1;   // vq swizzle (even -> preserves b128 pairing)
    const int s    = wave;
    const int ntiles = s + 1;

    const float kexp = 0.125f * 1.44269504088896f;   // scale * log2(e), folded into Q

    // ---------- Phase A: x fragments for own strip ----------
    short8 xa[2];
    {
        const float* xr = x + ((size_t)b * TB + s * 16 + lr) * CC;
#pragma unroll
        for (int kk = 0; kk < 2; ++kk) {
            const f32x4* p4 = (const f32x4*)(xr + kk * 32 + lg * 8);
            xa[kk] = pack8(p4[0], p4[1]);
        }
    }

    // ---------- Phase B: q^T,k^T = W@x^T (lane=pos); v = x@W^T (lane=h) — proven R5 ----------
    short8 qf[2];
    const float* Ws[3] = { Wq, Wk, Wv };
#pragma unroll
    for (int m = 0; m < 3; ++m) {
        f32x4 acc[4];
#pragma unroll
        for (int t = 0; t < 4; ++t) acc[t] = (f32x4){0.f, 0.f, 0.f, 0.f};
#pragma unroll
        for (int kk = 0; kk < 2; ++kk) {
            short8 wbk[4];
            if constexpr (WSF) {
#pragma unroll
                for (int t = 0; t < 4; ++t)
                    wbk[t] = wf[((m * 4 + t) * 2 + kk) * 64 + lane];
            } else {
#pragma unroll
                for (int t = 0; t < 4; ++t) {
                    const f32x4* p4 = (const f32x4*)(Ws[m] + (16 * t + lr) * CC + kk * 32 + lg * 8);
                    wbk[t] = pack8(p4[0], p4[1]);
                }
            }
#pragma unroll
            for (int t = 0; t < 4; ++t)
                acc[t] = (m < 2) ? MFMA16(wbk[t], xa[kk], acc[t])   // W in A slot -> transposed D
                                 : MFMA16(xa[kk], wbk[t], acc[t]);  // x in A slot -> standard D
        }
        if (m == 0) {
            // fold kexp into Q before bf16 pack (saves a mul per P elem in Phase C)
#pragma unroll
            for (int t = 0; t < 4; ++t)
#pragma unroll
                for (int e = 0; e < 4; ++e) acc[t][e] *= kexp;
#pragma unroll
            for (int kk = 0; kk < 2; ++kk)
                qf[kk] = pack8(acc[2 * kk], acc[2 * kk + 1]);
        } else if (m == 1) {
#pragma unroll
            for (int kk = 0; kk < 2; ++kk)
                kf_lds[((s * 2 + kk) * 4 + lg) * 16 + lr] = pack8(acc[2 * kk], acc[2 * kk + 1]);
        } else {
#pragma unroll
            for (int t = 0; t < 4; ++t)
                vq_lds[(lg * 64 + 16 * t + lr) * 16 + (s ^ xsw)] = pack4(acc[t]);
        }
    }
    __syncthreads();

    // ---------- Phase C: streaming causal attention (no row max; exact mask via P=0) ----------
    f32x4 o[4];
#pragma unroll
    for (int t = 0; t < 4; ++t) o[t] = (f32x4){0.f, 0.f, 0.f, 0.f};
    float sA = 0.f, sB = 0.f, sC = 0.f, sD = 0.f;

#pragma unroll
    for (int kt = 0; kt < 8; ++kt) {
        if (2 * kt < ntiles) {                      // wave-uniform branch
            const int j0 = 2 * kt, j1 = 2 * kt + 1;
            f32x4 p0 = (f32x4){0.f, 0.f, 0.f, 0.f};
            f32x4 p1 = (f32x4){0.f, 0.f, 0.f, 0.f};
#pragma unroll
            for (int kk = 0; kk < 2; ++kk)
                p0 = MFMA16(kf_lds[((j0 * 2 + kk) * 4 + lg) * 16 + lr], qf[kk], p0);
            const bool h1 = (j1 < ntiles);          // wave-uniform
            if (h1) {
#pragma unroll
                for (int kk = 0; kk < 2; ++kk)
                    p1 = MFMA16(kf_lds[((j1 * 2 + kk) * 4 + lg) * 16 + lr], qf[kk], p1);
            }
#pragma unroll
            for (int e = 0; e < 4; ++e) p0[e] = __builtin_amdgcn_exp2f(p0[e]);
            if (j0 == s) {                          // diagonal tile: exact causal zeroing
#pragma unroll
                for (int e = 0; e < 4; ++e) p0[e] = (4 * lg + e > lr) ? 0.f : p0[e];
            }
            if (h1) {
#pragma unroll
                for (int e = 0; e < 4; ++e) p1[e] = __builtin_amdgcn_exp2f(p1[e]);
                if (j1 == s) {
#pragma unroll
                    for (int e = 0; e < 4; ++e) p1[e] = (4 * lg + e > lr) ? 0.f : p1[e];
                }
            }
            sA += p0[0] + p1[0];
            sB += p0[1] + p1[1];
            sC += p0[2] + p1[2];
            sD += p0[3] + p1[3];

            short8 pa = pack8(p0, p1);              // p1 zeros when !h1 — benign
#pragma unroll
            for (int t = 0; t < 4; ++t) {
                const unsigned long long* vp =
                    &vq_lds[(lg * 64 + 16 * t + lr) * 16 + ((2 * kt) ^ xsw)];
                short8 vb = *(const short8*)vp;
                o[t] = MFMA16(pa, vb, o[t]);
            }
        }
    }
    float sm = (sA + sB) + (sC + sD);
    sm += __shfl_xor(sm, 16);
    sm += __shfl_xor(sm, 32);
    const float rinv = __builtin_amdgcn_rcpf(sm);

    // ---------- Epilogue: LDS restage (kf/vq dead) -> coalesced dwordx4 stores ----------
    __syncthreads();
    {
        float dn[4];
#pragma unroll
        for (int reg = 0; reg < 4; ++reg) dn[reg] = __shfl(rinv, 4 * lg + reg);
#pragma unroll
        for (int t = 0; t < 4; ++t)
#pragma unroll
            for (int reg = 0; reg < 4; ++reg) {
                const int row = 4 * lg + reg;                    // query row within strip
                const int col = (16 * t + lr) ^ (lg << 4);       // XOR key = row>>2 = lg
                stage[(s * 16 + row) * 64 + col] = o[t][reg] * dn[reg];
            }
        // own-wave data only: compiler inserts the lgkmcnt wait for the ds_write->ds_read dep
#pragma unroll
        for (int i = 0; i < 4; ++i) {
            const int row = 4 * i + lg;
            const int col = (4 * lr) ^ (i << 4);                 // XOR key = row>>2 = i
            f32x4 vv = *(const f32x4*)&stage[(s * 16 + row) * 64 + col];
            *(f32x4*)&out[((size_t)b * TB + 16 * s + row) * HH + 4 * lr] = vv;
        }
    }
}

extern "C" void kernel_launch(void* const* d_in, const int* in_sizes, int n_in,
                              void* d_out, int out_size, void* d_ws, size_t ws_size,
                              hipStream_t stream) {
    const float* x  = (const float*)d_in[0];
    const float* Wq = (const float*)d_in[1];
    const float* Wk = (const float*)d_in[2];
    const float* Wv = (const float*)d_in[3];
    float* out = (float*)d_out;
    const int Bn = in_sizes[0] / (TB * CC);   // 2048
    if (ws_size >= 3 * 4 * 2 * 64 * sizeof(short8)) {
        short8* wf = (short8*)d_ws;
        pack_w<<<1, 512, 0, stream>>>(Wq, Wk, Wv, wf);
        attn_fused<true><<<Bn, 1024, 0, stream>>>(x, Wq, Wk, Wv, wf, out);
    } else {
        attn_fused<false><<<Bn, 1024, 0, stream>>>(x, Wq, Wk, Wv, nullptr, out);
    }
}

// Round 15
// 65.868 us; speedup vs baseline: 1.5518x; 1.5518x over previous
//
#include <hip/hip_runtime.h>
#include <hip/hip_bf16.h>

#define TB 256   // T (sequence length)
#define CC 64    // C (embed)
#define HH 64    // H (head size)

typedef __attribute__((ext_vector_type(8))) short short8;   // 8 bf16 (4 VGPRs)
typedef __attribute__((ext_vector_type(4))) float f32x4;    // MFMA C/D frag

#define MFMA16(a, b, c) __builtin_amdgcn_mfma_f32_16x16x32_bf16((a), (b), (c), 0, 0, 0)

// Packed f32->bf16 pair via HIP intrinsic (lowers to v_cvt_pk_bf16_f32) — proven R12.
__device__ __forceinline__ unsigned cvt2(float lo, float hi) {
    union { __hip_bfloat162 h2; unsigned u; } cv;
    cv.h2 = __float22bfloat162_rn(make_float2(lo, hi));
    return cv.u;
}

union S8U { short8 s8; unsigned u32[4]; unsigned long long u64[2]; };

__device__ __forceinline__ short8 pack8(f32x4 a, f32x4 b) {
    S8U r;
    r.u32[0] = cvt2(a[0], a[1]);
    r.u32[1] = cvt2(a[2], a[3]);
    r.u32[2] = cvt2(b[0], b[1]);
    r.u32[3] = cvt2(b[2], b[3]);
    return r.s8;
}

__device__ __forceinline__ unsigned long long pack4(f32x4 a) {
    S8U r;
    r.u32[0] = cvt2(a[0], a[1]);
    r.u32[1] = cvt2(a[2], a[3]);
    return r.u64[0];
}

// Pre-kernel: W -> MFMA-ready bf16 fragments (proven R4). Layout byte-identical to wb frags.
__global__ __launch_bounds__(512, 1)
void pack_w(const float* __restrict__ Wq, const float* __restrict__ Wk,
            const float* __restrict__ Wv, short8* __restrict__ wf) {
    const int tid  = threadIdx.x;
    const int lane = tid & 63;
    const int lr   = lane & 15;
    const int lg   = lane >> 4;
    const int idx  = tid >> 6;        // 0..7
    const int t    = idx >> 1;
    const int kk   = idx & 1;
    const float* Ws[3] = { Wq, Wk, Wv };
#pragma unroll
    for (int m = 0; m < 3; ++m) {
        const f32x4* p4 = (const f32x4*)(Ws[m] + (16 * t + lr) * CC + kk * 32 + lg * 8);
        wf[((m * 4 + t) * 2 + kk) * 64 + lane] = pack8(p4[0], p4[1]);
    }
}

// R12 shell (proven 66.5us) + denominator-via-ones-MFMA:
// o4 = sum_k P[row][k] computed by one extra MFMA per (strip, tile-pair) with an
// all-ones B tile — replaces 136 VALU adds + 6 cross-lane ops per wave, and makes
// num/denom use the IDENTICAL bf16-quantized P. dn needs no shuffle (replicated).
template<bool WSF>
__global__ __launch_bounds__(512, 4)
void attn_fused(const float* __restrict__ x, const float* __restrict__ Wq,
                const float* __restrict__ Wk, const float* __restrict__ Wv,
                const short8* __restrict__ wf, float* __restrict__ out)
{
    // 64 KiB shared, phase-aliased: Phase B/C: kf(32K)+vq(32K); epilogue: fp32 stage[256][64]
    __shared__ __align__(16) char smem[65536];
    short8* kf_lds = (short8*)smem;                                   // [16][2][4][16]
    unsigned long long* vq_lds = (unsigned long long*)(smem + 32768); // [4][64][16]
    float* stage = (float*)smem;

    const int b    = blockIdx.x;
    const int tid  = threadIdx.x;
    const int wave = tid >> 6;
    const int lane = tid & 63;
    const int lr   = lane & 15;
    const int lg   = lane >> 4;
    const int xsw  = (lr & 7) << 1;   // vq swizzle (even -> preserves b128 pairing)

    const int sA = wave;              // light strip (ntA <= 8)
    const int sB = 15 - wave;         // heavy strip (ntB >= 9)
    const int ntA = sA + 1;
    const int ntB = sB + 1;

    const float kexp = 0.125f * 1.44269504088896f;   // scale * log2(e), folded into Q

    // all-ones bf16 B-tile fragment (0x3F80 = bf16 1.0)
    const short8 ones = { (short)0x3F80, (short)0x3F80, (short)0x3F80, (short)0x3F80,
                          (short)0x3F80, (short)0x3F80, (short)0x3F80, (short)0x3F80 };

    // ---------- Phase A: x fragments for both strips ----------
    short8 xa[2][2];
#pragma unroll
    for (int sp = 0; sp < 2; ++sp) {
        const int s = sp ? sB : sA;
        const float* xr = x + ((size_t)b * TB + s * 16 + lr) * CC;
#pragma unroll
        for (int kk = 0; kk < 2; ++kk) {
            const f32x4* p4 = (const f32x4*)(xr + kk * 32 + lg * 8);
            xa[sp][kk] = pack8(p4[0], p4[1]);
        }
    }

    // ---------- Phase B: q^T,k^T = W@x^T (lane=pos); v = x@W^T (lane=h) — proven R4 ----------
    short8 qfA[2], qfB[2];
    const float* Ws[3] = { Wq, Wk, Wv };
#pragma unroll
    for (int m = 0; m < 3; ++m) {
        short8 wb[4][2];
        if constexpr (WSF) {
#pragma unroll
            for (int t = 0; t < 4; ++t)
#pragma unroll
                for (int kk = 0; kk < 2; ++kk)
                    wb[t][kk] = wf[((m * 4 + t) * 2 + kk) * 64 + lane];
        } else {
#pragma unroll
            for (int t = 0; t < 4; ++t)
#pragma unroll
                for (int kk = 0; kk < 2; ++kk) {
                    const f32x4* p4 = (const f32x4*)(Ws[m] + (16 * t + lr) * CC + kk * 32 + lg * 8);
                    wb[t][kk] = pack8(p4[0], p4[1]);
                }
        }
#pragma unroll
        for (int sp = 0; sp < 2; ++sp) {
            const int s = sp ? sB : sA;
            f32x4 acc[4];
#pragma unroll
            for (int t = 0; t < 4; ++t) acc[t] = (f32x4){0.f, 0.f, 0.f, 0.f};
#pragma unroll
            for (int kk = 0; kk < 2; ++kk)
#pragma unroll
                for (int t = 0; t < 4; ++t)
                    acc[t] = (m < 2) ? MFMA16(wb[t][kk], xa[sp][kk], acc[t])   // W in A slot -> transposed D
                                     : MFMA16(xa[sp][kk], wb[t][kk], acc[t]);  // x in A slot -> standard D

            if (m == 0) {
                // fold kexp into Q before bf16 pack (saves a mul per P elem in Phase C)
#pragma unroll
                for (int t = 0; t < 4; ++t)
#pragma unroll
                    for (int e = 0; e < 4; ++e) acc[t][e] *= kexp;
#pragma unroll
                for (int kk = 0; kk < 2; ++kk) {
                    short8 q = pack8(acc[2 * kk], acc[2 * kk + 1]);
                    if (sp) qfB[kk] = q; else qfA[kk] = q;
                }
            } else if (m == 1) {
#pragma unroll
                for (int kk = 0; kk < 2; ++kk)
                    kf_lds[((s * 2 + kk) * 4 + lg) * 16 + lr] = pack8(acc[2 * kk], acc[2 * kk + 1]);
            } else {
#pragma unroll
                for (int t = 0; t < 4; ++t)
                    vq_lds[(lg * 64 + 16 * t + lr) * 16 + (s ^ xsw)] = pack4(acc[t]);
            }
        }
    }
    __syncthreads();

    // ---------- Phase C: streaming causal attention; loads hoisted & shared (R11/R12) ----------
    f32x4 oA[4], oB[4];
#pragma unroll
    for (int t = 0; t < 4; ++t) {
        oA[t] = (f32x4){0.f, 0.f, 0.f, 0.f};
        oB[t] = (f32x4){0.f, 0.f, 0.f, 0.f};
    }
    f32x4 o4A = (f32x4){0.f, 0.f, 0.f, 0.f};   // row-sum accumulators (denominator)
    f32x4 o4B = (f32x4){0.f, 0.f, 0.f, 0.f};

#pragma unroll
    for (int kt = 0; kt < 8; ++kt) {
        const int j0 = 2 * kt, j1 = 2 * kt + 1;

        // ---- UNGUARDED shared loads (always in-bounds: kf has 16 tiles, vb slots even<=14) ----
        const short8 kf0a = kf_lds[((j0 * 2 + 0) * 4 + lg) * 16 + lr];
        const short8 kf0b = kf_lds[((j0 * 2 + 1) * 4 + lg) * 16 + lr];
        const short8 kf1a = kf_lds[((j1 * 2 + 0) * 4 + lg) * 16 + lr];
        const short8 kf1b = kf_lds[((j1 * 2 + 1) * 4 + lg) * 16 + lr];
        const short8 vb0 = *(const short8*)&vq_lds[(lg * 64 +  0 + lr) * 16 + (j0 ^ xsw)];
        const short8 vb1 = *(const short8*)&vq_lds[(lg * 64 + 16 + lr) * 16 + (j0 ^ xsw)];
        const short8 vb2 = *(const short8*)&vq_lds[(lg * 64 + 32 + lr) * 16 + (j0 ^ xsw)];
        const short8 vb3 = *(const short8*)&vq_lds[(lg * 64 + 48 + lr) * 16 + (j0 ^ xsw)];

        // ---- strip A tile-pair kt ----
        if (2 * kt < ntA) {
            f32x4 p0 = (f32x4){0.f, 0.f, 0.f, 0.f};
            f32x4 p1 = (f32x4){0.f, 0.f, 0.f, 0.f};
            p0 = MFMA16(kf0a, qfA[0], p0);
            p0 = MFMA16(kf0b, qfA[1], p0);
            const bool h1 = (j1 < ntA);
            if (h1) {
                p1 = MFMA16(kf1a, qfA[0], p1);
                p1 = MFMA16(kf1b, qfA[1], p1);
            }
#pragma unroll
            for (int e = 0; e < 4; ++e) p0[e] = __builtin_amdgcn_exp2f(p0[e]);
            if (j0 == sA) {
#pragma unroll
                for (int e = 0; e < 4; ++e) p0[e] = (4 * lg + e > lr) ? 0.f : p0[e];
            }
            if (h1) {
#pragma unroll
                for (int e = 0; e < 4; ++e) p1[e] = __builtin_amdgcn_exp2f(p1[e]);
                if (j1 == sA) {
#pragma unroll
                    for (int e = 0; e < 4; ++e) p1[e] = (4 * lg + e > lr) ? 0.f : p1[e];
                }
            }
            short8 pa = pack8(p0, p1);
            oA[0] = MFMA16(pa, vb0, oA[0]);
            oA[1] = MFMA16(pa, vb1, oA[1]);
            oA[2] = MFMA16(pa, vb2, oA[2]);
            oA[3] = MFMA16(pa, vb3, oA[3]);
            o4A   = MFMA16(pa, ones, o4A);     // denominator: row-sum of the SAME bf16 P
        }

        // ---- strip B tile-pair kt ----
        if (2 * kt < ntB) {
            f32x4 p0 = (f32x4){0.f, 0.f, 0.f, 0.f};
            f32x4 p1 = (f32x4){0.f, 0.f, 0.f, 0.f};
            p0 = MFMA16(kf0a, qfB[0], p0);
            p0 = MFMA16(kf0b, qfB[1], p0);
            const bool h1 = (j1 < ntB);
            if (h1) {
                p1 = MFMA16(kf1a, qfB[0], p1);
                p1 = MFMA16(kf1b, qfB[1], p1);
            }
#pragma unroll
            for (int e = 0; e < 4; ++e) p0[e] = __builtin_amdgcn_exp2f(p0[e]);
            if (j0 == sB) {
#pragma unroll
                for (int e = 0; e < 4; ++e) p0[e] = (4 * lg + e > lr) ? 0.f : p0[e];
            }
            if (h1) {
#pragma unroll
                for (int e = 0; e < 4; ++e) p1[e] = __builtin_amdgcn_exp2f(p1[e]);
                if (j1 == sB) {
#pragma unroll
                    for (int e = 0; e < 4; ++e) p1[e] = (4 * lg + e > lr) ? 0.f : p1[e];
                }
            }
            short8 pa = pack8(p0, p1);
            oB[0] = MFMA16(pa, vb0, oB[0]);
            oB[1] = MFMA16(pa, vb1, oB[1]);
            oB[2] = MFMA16(pa, vb2, oB[2]);
            oB[3] = MFMA16(pa, vb3, oB[3]);
            o4B   = MFMA16(pa, ones, o4B);
        }
    }

    // ---------- Epilogue: LDS restage (kf/vq dead) -> coalesced dwordx4 stores — proven R4 ----------
    __syncthreads();
#pragma unroll
    for (int sp = 0; sp < 2; ++sp) {
        const int s = sp ? sB : sA;
        const f32x4 o4 = sp ? o4B : o4A;
        float dn[4];
#pragma unroll
        for (int reg = 0; reg < 4; ++reg) dn[reg] = __builtin_amdgcn_rcpf(o4[reg]);
#pragma unroll
        for (int t = 0; t < 4; ++t)
#pragma unroll
            for (int reg = 0; reg < 4; ++reg) {
                const int row = 4 * lg + reg;                    // query row within strip
                const int col = (16 * t + lr) ^ (lg << 4);       // XOR key = row>>2 = lg
                const f32x4 o = sp ? oB[t] : oA[t];
                stage[(s * 16 + row) * 64 + col] = o[reg] * dn[reg];
            }
    }
    // own-wave data only: compiler inserts the lgkmcnt wait for the ds_write->ds_read dep
#pragma unroll
    for (int sp = 0; sp < 2; ++sp) {
        const int s = sp ? sB : sA;
#pragma unroll
        for (int i = 0; i < 4; ++i) {
            const int row = 4 * i + lg;
            const int col = (4 * lr) ^ (i << 4);                 // XOR key = row>>2 = i
            f32x4 vv = *(const f32x4*)&stage[(s * 16 + row) * 64 + col];
            *(f32x4*)&out[((size_t)b * TB + 16 * s + row) * HH + 4 * lr] = vv;
        }
    }
}

extern "C" void kernel_launch(void* const* d_in, const int* in_sizes, int n_in,
                              void* d_out, int out_size, void* d_ws, size_t ws_size,
                              hipStream_t stream) {
    const float* x  = (const float*)d_in[0];
    const float* Wq = (const float*)d_in[1];
    const float* Wk = (const float*)d_in[2];
    const float* Wv = (const float*)d_in[3];
    float* out = (float*)d_out;
    const int Bn = in_sizes[0] / (TB * CC);   // 2048
    if (ws_size >= 3 * 4 * 2 * 64 * sizeof(short8)) {
        short8* wf = (short8*)d_ws;
        pack_w<<<1, 512, 0, stream>>>(Wq, Wk, Wv, wf);
        attn_fused<true><<<Bn, 512, 0, stream>>>(x, Wq, Wk, Wv, wf, out);
    } else {
        attn_fused<false><<<Bn, 512, 0, stream>>>(x, Wq, Wk, Wv, nullptr, out);
    }
}